// Round 1
// baseline (1915.772 us; speedup 1.0000x reference)
//
#include <hip/hip_runtime.h>
#include <hip/hip_bf16.h>

namespace {

constexpr int HID = 256;
constexpr int NH  = 8;
constexpr int OBS = 72;
constexpr int INW = 87;
constexpr int RB  = 16;   // rows per block
constexpr int NT  = 256;  // threads per block

struct SMem {
  float x[RB][88];                      // staged input rows (padded 87->88)
  float buf0[RB][HID];                  // enc_in -> enc_h -> context
  float buf1[RB][HID];                  // dec_in
  __hip_bfloat16 heads[NH][RB][HID];    // all 8 head tiles (bf16 to fit LDS)
  float scores[RB][NH];
  float attn[RB][NH];
};
// sizeof(SMem) = 5632 + 16384*2 + 65536 + 512 + 512 = 104960 B  (< 160 KiB)

// C[r][c] = act(bias[c] + sum_i inb[r][i] * W[i*256 + c]) for this thread's
// 2 rows (r0, r0+1) x 8 columns (cg + 32*j).  K = 256.
__device__ __forceinline__ void gemm256(const float (&inb)[RB][HID],
                                        const float* __restrict__ W,
                                        const float* __restrict__ bias,
                                        int cg, int r0,
                                        float (&o)[2][8], bool do_relu)
{
  float acc[2][8];
#pragma unroll
  for (int j = 0; j < 8; ++j) {
    const float bv = bias[cg + 32 * j];
    acc[0][j] = bv;
    acc[1][j] = bv;
  }
  for (int i = 0; i < HID; i += 4) {
    const float4 a0 = *reinterpret_cast<const float4*>(&inb[r0][i]);
    const float4 a1 = *reinterpret_cast<const float4*>(&inb[r0 + 1][i]);
    const float av[2][4] = {{a0.x, a0.y, a0.z, a0.w}, {a1.x, a1.y, a1.z, a1.w}};
#pragma unroll
    for (int ii = 0; ii < 4; ++ii) {
      float w[8];
#pragma unroll
      for (int j = 0; j < 8; ++j) w[j] = W[(i + ii) * HID + cg + 32 * j];
#pragma unroll
      for (int k = 0; k < 2; ++k) {
        const float avk = av[k][ii];
#pragma unroll
        for (int j = 0; j < 8; ++j) acc[k][j] = fmaf(avk, w[j], acc[k][j]);
      }
    }
  }
#pragma unroll
  for (int k = 0; k < 2; ++k)
#pragma unroll
    for (int j = 0; j < 8; ++j)
      o[k][j] = do_relu ? fmaxf(acc[k][j], 0.f) : acc[k][j];
}

__global__ __launch_bounds__(NT, 1)
void fused_mlp_attn(const float* __restrict__ x,
                    const float* __restrict__ Wfc1, const float* __restrict__ bfc1,
                    const float* __restrict__ Wfc2, const float* __restrict__ bfc2,
                    const float* __restrict__ Wenc, const float* __restrict__ benc,
                    const float* __restrict__ Whds, const float* __restrict__ bhds,
                    const float* __restrict__ Wdec, const float* __restrict__ bdec,
                    const float* __restrict__ Wfc3, const float* __restrict__ bfc3,
                    const float* __restrict__ Wq,  const float* __restrict__ bq,
                    const int* __restrict__ agent,
                    float* __restrict__ out)
{
  __shared__ SMem s;
  const int tid = (int)threadIdx.x;
  const int cg  = tid & 31;   // column lane: columns cg + 32*j, j=0..7
  const int rg  = tid >> 5;   // row group 0..7
  const int r0  = rg * 2;     // first of this thread's 2 rows
  const int row0 = (int)blockIdx.x * RB;
  const int a = agent[0];     // 0..2

  // ---- stage x tile ----
  for (int idx = tid; idx < RB * INW; idx += NT) {
    const int r = idx / INW;
    const int i = idx - r * INW;
    s.x[r][i] = x[(size_t)(row0 + r) * INW + i];
  }
  __syncthreads();

  // ---- fc1: [x[:, :72], act_self] @ Wfc1 + b  -> buf0 (no relu), K=77 ----
  {
    float acc[2][8];
#pragma unroll
    for (int j = 0; j < 8; ++j) {
      const float bv = bfc1[cg + 32 * j];
      acc[0][j] = bv; acc[1][j] = bv;
    }
    for (int i = 0; i < 77; ++i) {
      const int xi = (i < OBS) ? i : (i + 5 * a);
      float w[8];
#pragma unroll
      for (int j = 0; j < 8; ++j) w[j] = Wfc1[i * HID + cg + 32 * j];
#pragma unroll
      for (int k = 0; k < 2; ++k) {
        const float av = s.x[r0 + k][xi];
#pragma unroll
        for (int j = 0; j < 8; ++j) acc[k][j] = fmaf(av, w[j], acc[k][j]);
      }
    }
#pragma unroll
    for (int k = 0; k < 2; ++k)
#pragma unroll
      for (int j = 0; j < 8; ++j) s.buf0[r0 + k][cg + 32 * j] = acc[k][j];
  }

  // ---- fc2: act_others @ Wfc2 + b -> buf1 (no relu), K=10 ----
  {
    float acc[2][8];
#pragma unroll
    for (int j = 0; j < 8; ++j) {
      const float bv = bfc2[cg + 32 * j];
      acc[0][j] = bv; acc[1][j] = bv;
    }
    for (int i = 0; i < 10; ++i) {
      const int xi = OBS + ((i < 5 * a) ? i : (i + 5));
      float w[8];
#pragma unroll
      for (int j = 0; j < 8; ++j) w[j] = Wfc2[i * HID + cg + 32 * j];
#pragma unroll
      for (int k = 0; k < 2; ++k) {
        const float av = s.x[r0 + k][xi];
#pragma unroll
        for (int j = 0; j < 8; ++j) acc[k][j] = fmaf(av, w[j], acc[k][j]);
      }
    }
#pragma unroll
    for (int k = 0; k < 2; ++k)
#pragma unroll
      for (int j = 0; j < 8; ++j) s.buf1[r0 + k][cg + 32 * j] = acc[k][j];
  }
  __syncthreads();

  // ---- enc_h = relu(buf0 @ Wenc + b) -> regs ; dec_H = relu(buf1 @ Wdec + b) -> regs ----
  float ench[2][8], dH[2][8];
  gemm256(s.buf0, Wenc, benc, cg, r0, ench, true);
  gemm256(s.buf1, Wdec, bdec, cg, r0, dH, true);
  __syncthreads();

  // ---- park enc_h in buf0 for the head GEMMs ----
#pragma unroll
  for (int k = 0; k < 2; ++k)
#pragma unroll
    for (int j = 0; j < 8; ++j) s.buf0[r0 + k][cg + 32 * j] = ench[k][j];
  __syncthreads();

  // ---- heads: per h, head = relu(enc_h @ Whds[h] + b); score partial; stash bf16 ----
  float sp[2][NH];
  for (int h = 0; h < NH; ++h) {
    float hd[2][8];
    gemm256(s.buf0, Whds + (size_t)h * HID * HID, bhds + h * HID, cg, r0, hd, true);
#pragma unroll
    for (int k = 0; k < 2; ++k) {
      float p = 0.f;
#pragma unroll
      for (int j = 0; j < 8; ++j) p = fmaf(hd[k][j], dH[k][j], p);
      sp[k][h] = p;
    }
#pragma unroll
    for (int k = 0; k < 2; ++k)
#pragma unroll
      for (int j = 0; j < 8; ++j)
        s.heads[h][r0 + k][cg + 32 * j] = __float2bfloat16(hd[k][j]);
  }

  // ---- reduce score partials across the 32 column lanes ----
#pragma unroll
  for (int k = 0; k < 2; ++k)
#pragma unroll
    for (int h = 0; h < NH; ++h) {
      float v = sp[k][h];
#pragma unroll
      for (int m = 16; m >= 1; m >>= 1) v += __shfl_xor(v, m, 64);
      if (cg == 0) s.scores[r0 + k][h] = v;
    }
  __syncthreads();

  // ---- softmax over heads (one thread per row; 16 rows) ----
  if (tid < RB) {
    float sc[NH];
    float mx = -3.4e38f;
#pragma unroll
    for (int h = 0; h < NH; ++h) { sc[h] = s.scores[tid][h]; mx = fmaxf(mx, sc[h]); }
    float sum = 0.f;
#pragma unroll
    for (int h = 0; h < NH; ++h) { sc[h] = __expf(sc[h] - mx); sum += sc[h]; }
    const float inv = 1.f / sum;
#pragma unroll
    for (int h = 0; h < NH; ++h) s.attn[tid][h] = sc[h] * inv;
  }
  __syncthreads();

  // ---- context = sum_h attn[h] * heads[h] ----
  float ctx[2][8];
#pragma unroll
  for (int k = 0; k < 2; ++k)
#pragma unroll
    for (int j = 0; j < 8; ++j) ctx[k][j] = 0.f;
  for (int h = 0; h < NH; ++h) {
    const float aw0 = s.attn[r0][h];
    const float aw1 = s.attn[r0 + 1][h];
#pragma unroll
    for (int j = 0; j < 8; ++j) {
      ctx[0][j] = fmaf(aw0, __bfloat162float(s.heads[h][r0][cg + 32 * j]), ctx[0][j]);
      ctx[1][j] = fmaf(aw1, __bfloat162float(s.heads[h][r0 + 1][cg + 32 * j]), ctx[1][j]);
    }
  }
  // buf0 (enc_h) is dead now; every thread passed the scores barrier.
#pragma unroll
  for (int k = 0; k < 2; ++k)
#pragma unroll
    for (int j = 0; j < 8; ++j) s.buf0[r0 + k][cg + 32 * j] = ctx[k][j];
  __syncthreads();

  // ---- t1 = relu(ctx @ Wfc3 + b) ----
  float t1[2][8];
  gemm256(s.buf0, Wfc3, bfc3, cg, r0, t1, true);

  // ---- out = t1 @ Wq + bq  (reduce 8 cols/thread, then 32 lanes) ----
  const float bq0 = bq[0];
#pragma unroll
  for (int k = 0; k < 2; ++k) {
    float v = 0.f;
#pragma unroll
    for (int j = 0; j < 8; ++j) v = fmaf(t1[k][j], Wq[cg + 32 * j], v);
#pragma unroll
    for (int m = 16; m >= 1; m >>= 1) v += __shfl_xor(v, m, 64);
    if (cg == 0) out[row0 + r0 + k] = v + bq0;
  }
}

}  // namespace

extern "C" void kernel_launch(void* const* d_in, const int* in_sizes, int n_in,
                              void* d_out, int out_size, void* d_ws, size_t ws_size,
                              hipStream_t stream) {
  const float* x    = (const float*)d_in[0];
  const float* Wfc1 = (const float*)d_in[1];
  const float* bfc1 = (const float*)d_in[2];
  const float* Wfc2 = (const float*)d_in[3];
  const float* bfc2 = (const float*)d_in[4];
  const float* Wenc = (const float*)d_in[5];
  const float* benc = (const float*)d_in[6];
  const float* Whds = (const float*)d_in[7];
  const float* bhds = (const float*)d_in[8];
  const float* Wdec = (const float*)d_in[9];
  const float* bdec = (const float*)d_in[10];
  const float* Wfc3 = (const float*)d_in[11];
  const float* bfc3 = (const float*)d_in[12];
  const float* Wq   = (const float*)d_in[13];
  const float* bq   = (const float*)d_in[14];
  const int*   agent = (const int*)d_in[15];
  float* out = (float*)d_out;

  const int Bn = in_sizes[0] / INW;       // 32768
  const int grid = Bn / RB;               // 2048 blocks

  fused_mlp_attn<<<grid, NT, 0, stream>>>(x, Wfc1, bfc1, Wfc2, bfc2, Wenc, benc,
                                          Whds, bhds, Wdec, bdec, Wfc3, bfc3,
                                          Wq, bq, agent, out);
}

// Round 2
// 312.698 us; speedup vs baseline: 6.1266x; 6.1266x over previous
//
#include <hip/hip_runtime.h>
#include <hip/hip_bf16.h>

typedef _Float16 half8 __attribute__((ext_vector_type(8)));
typedef _Float16 half4 __attribute__((ext_vector_type(4)));
typedef _Float16 half2v __attribute__((ext_vector_type(2)));
typedef float f32x4 __attribute__((ext_vector_type(4)));

namespace {

constexpr int HID  = 256;
constexpr int INW  = 87;
constexpr int ROWS = 128;   // rows per block
constexpr int NT   = 512;   // 8 waves

// A panel [128][256] fp16, chunk-XOR swizzle: elem index for (row, col)
__device__ __forceinline__ int aidx(int row, int col) {
  return row * 256 + ((((col >> 3) ^ (row & 7)) << 3) | (col & 7));
}
// B slice [256 n][64 k] fp16 (n-major), chunk-XOR swizzle
__device__ __forceinline__ int bidx(int n, int chunk, int sub) {
  return n * 64 + (((chunk ^ ((n >> 1) & 7)) << 3) | sub);
}

__global__ __launch_bounds__(NT, 2)
void fused_mfma(const float* __restrict__ x,
                const float* __restrict__ Wfc1, const float* __restrict__ bfc1,
                const float* __restrict__ Wfc2, const float* __restrict__ bfc2,
                const float* __restrict__ Wenc, const float* __restrict__ benc,
                const float* __restrict__ Whds, const float* __restrict__ bhds,
                const float* __restrict__ Wdec, const float* __restrict__ bdec,
                const float* __restrict__ Wfc3, const float* __restrict__ bfc3,
                const float* __restrict__ Wq,  const float* __restrict__ bq,
                const int* __restrict__ agent,
                float* __restrict__ out)
{
  __shared__ _Float16 A[ROWS * 256];      // 64 KB
  __shared__ _Float16 Bs[2][64 * 256];    // 2 x 32 KB
  __shared__ float sp[4 * ROWS];          // 2 KB

  const int tid  = (int)threadIdx.x;
  const int lane = tid & 63;
  const int wave = tid >> 6;
  const int l15  = lane & 15;
  const int l4   = lane >> 4;
  const int wm   = wave >> 2;       // 0..1
  const int wn   = wave & 3;        // 0..3
  const int rbase = wm * 64;
  const int cbase = wn * 64;
  const int row0 = (int)blockIdx.x * ROWS;
  const int a = agent[0];

  // ---------------- build A0 [128][128] (cols 87..127 = 0) ----------------
  for (int i = tid; i < ROWS * 128; i += NT) {
    const int r = i >> 7, c = i & 127;
    float v = 0.f;
    const size_t xb = (size_t)(row0 + r) * INW;
    if (c < 72)       v = x[xb + c];
    else if (c < 77)  v = x[xb + 72 + 5 * a + (c - 72)];
    else if (c < 87) {
      const int o = c - 77;
      v = x[xb + 72 + (o < 5 * a ? o : o + 5)];
    }
    A[aidx(r, c)] = (_Float16)v;
  }
  __syncthreads();

  // ---------------- staging helpers ----------------
  auto stage256 = [&](const float* __restrict__ W, int s, _Float16* buf) {
#pragma unroll
    for (int i = 0; i < 8; ++i) {
      const int task = i * NT + tid;
      const int n = task & 255, kq = task >> 8;         // kq 0..15
      const int k = s * 64 + kq * 4;
      const float* wp = W + (size_t)k * 256 + n;
      half4 v = { (_Float16)wp[0], (_Float16)wp[256],
                  (_Float16)wp[512], (_Float16)wp[768] };
      *(half4*)&buf[bidx(n, kq >> 1, (kq & 1) * 4)] = v;
    }
  };
  // fc combined-B: h==0 -> enc cols (Wfc1, k rows 0..76); h==1 -> dec cols (Wfc2 at k-77)
  auto stageFC = [&](int h, int s, _Float16* buf) {
#pragma unroll
    for (int i = 0; i < 8; ++i) {
      const int task = i * NT + tid;
      const int n = task & 255, kq = task >> 8;
      const int k = s * 64 + kq * 4;
      float w[4];
#pragma unroll
      for (int e = 0; e < 4; ++e) {
        const int kk = k + e;
        float vv = 0.f;
        if (h == 0) { if (kk < 77) vv = Wfc1[(size_t)kk * 256 + n]; }
        else        { if (kk >= 77 && kk < 87) vv = Wfc2[(size_t)(kk - 77) * 256 + n]; }
        w[e] = vv;
      }
      half4 v = { (_Float16)w[0], (_Float16)w[1], (_Float16)w[2], (_Float16)w[3] };
      *(half4*)&buf[bidx(n, kq >> 1, (kq & 1) * 4)] = v;
    }
  };

  auto computeSlice = [&](const _Float16* __restrict__ buf, int kchunk0,
                          f32x4 (&acc)[4][4]) {
#pragma unroll
    for (int ksl = 0; ksl < 2; ++ksl) {
      half8 af[4], bf[4];
#pragma unroll
      for (int mt = 0; mt < 4; ++mt) {
        const int row = rbase + mt * 16 + l15;      // A-frag: row = lane&15
        const int kc  = kchunk0 + ksl * 4 + l4;     // k = (lane>>4)*8 contiguous
        af[mt] = *(const half8*)&A[row * 256 + ((kc ^ (row & 7)) << 3)];
      }
#pragma unroll
      for (int nt = 0; nt < 4; ++nt) {
        const int n  = cbase + nt * 16 + l15;       // B-frag: col = lane&15
        const int ch = ksl * 4 + l4;
        bf[nt] = *(const half8*)&buf[n * 64 + ((ch ^ ((n >> 1) & 7)) << 3)];
      }
#pragma unroll
      for (int mt = 0; mt < 4; ++mt)
#pragma unroll
        for (int nt = 0; nt < 4; ++nt)
          acc[mt][nt] = __builtin_amdgcn_mfma_f32_16x16x32_f16(
              af[mt], bf[nt], acc[mt][nt], 0, 0, 0);
    }
  };

  auto initAcc = [&](const float* __restrict__ bias, f32x4 (&acc)[4][4]) {
#pragma unroll
    for (int nt = 0; nt < 4; ++nt) {
      const float bv = bias[cbase + nt * 16 + l15];
#pragma unroll
      for (int mt = 0; mt < 4; ++mt) acc[mt][nt] = { bv, bv, bv, bv };
    }
  };

  auto gemm256 = [&](const float* __restrict__ W, const float* __restrict__ bias,
                     f32x4 (&acc)[4][4]) {
    initAcc(bias, acc);
    for (int s = 0; s < 4; ++s) {
      stage256(W, s, Bs[s & 1]);
      __syncthreads();
      computeSlice(Bs[s & 1], s * 8, acc);
      __syncthreads();
    }
  };
  auto gemmFC = [&](int h, const float* __restrict__ bias, f32x4 (&acc)[4][4]) {
    initAcc(bias, acc);
    for (int s = 0; s < 2; ++s) {
      stageFC(h, s, Bs[s & 1]);
      __syncthreads();
      computeSlice(Bs[s & 1], s * 8, acc);
      __syncthreads();
    }
  };

  // write acc (C-frag layout: col=lane&15, row=(lane>>4)*4+reg) into A panel
  auto writeA = [&](const f32x4 (&acc)[4][4], bool relu) {
#pragma unroll
    for (int mt = 0; mt < 4; ++mt)
#pragma unroll
      for (int nt = 0; nt < 4; ++nt)
#pragma unroll
        for (int r = 0; r < 4; ++r) {
          float v = acc[mt][nt][r];
          if (relu) v = fmaxf(v, 0.f);
          const int row = rbase + mt * 16 + l4 * 4 + r;
          const int col = cbase + nt * 16 + l15;
          A[aidx(row, col)] = (_Float16)v;
        }
  };

  // ---------------- fc1 / fc2 (K=128 padded) ----------------
  f32x4 accD[4][4], accE[4][4];
  gemmFC(1, bfc2, accD);          // dec_in (linear)
  gemmFC(0, bfc1, accE);          // enc_in (linear)

  writeA(accD, false);            // A := dec_in
  __syncthreads();

  f32x4 acc[4][4];
  gemm256(Wdec, bdec, acc);       // dec_in @ Wdec + b
  half2v dpk[4][4][2];            // dec_H = relu(...), packed fp16
#pragma unroll
  for (int mt = 0; mt < 4; ++mt)
#pragma unroll
    for (int nt = 0; nt < 4; ++nt)
#pragma unroll
      for (int rh = 0; rh < 2; ++rh) {
        dpk[mt][nt][rh] = half2v{
          (_Float16)fmaxf(acc[mt][nt][2 * rh], 0.f),
          (_Float16)fmaxf(acc[mt][nt][2 * rh + 1], 0.f) };
      }

  writeA(accE, false);            // A := enc_in
  __syncthreads();
  gemm256(Wenc, benc, acc);       // enc_h
  writeA(acc, true);              // A := relu(enc_h)
  __syncthreads();

  // ---------------- heads with online softmax (reference = head 0 score) ----------------
  f32x4 ctx[4][4];
#pragma unroll
  for (int mt = 0; mt < 4; ++mt)
#pragma unroll
    for (int nt = 0; nt < 4; ++nt) ctx[mt][nt] = { 0.f, 0.f, 0.f, 0.f };
  float s0[4][4], lsum[4][4];

  for (int h = 0; h < 8; ++h) {
    gemm256(Whds + (size_t)h * HID * HID, bhds + h * HID, acc);
#pragma unroll
    for (int mt = 0; mt < 4; ++mt)
#pragma unroll
      for (int nt = 0; nt < 4; ++nt)
#pragma unroll
        for (int r = 0; r < 4; ++r) acc[mt][nt][r] = fmaxf(acc[mt][nt][r], 0.f);

    // score partials: p[mt][r] = sum_nt head * dec_H
    float p[4][4];
#pragma unroll
    for (int mt = 0; mt < 4; ++mt)
#pragma unroll
      for (int r = 0; r < 4; ++r) {
        float v = 0.f;
#pragma unroll
        for (int nt = 0; nt < 4; ++nt)
          v = fmaf(acc[mt][nt][r], (float)dpk[mt][nt][r >> 1][r & 1], v);
        p[mt][r] = v;
      }
#pragma unroll
    for (int off = 1; off < 16; off <<= 1)
#pragma unroll
      for (int mt = 0; mt < 4; ++mt)
#pragma unroll
        for (int r = 0; r < 4; ++r)
          p[mt][r] += __shfl_xor(p[mt][r], off, 64);
    if (l15 == 0) {
#pragma unroll
      for (int mt = 0; mt < 4; ++mt)
#pragma unroll
        for (int r = 0; r < 4; ++r)
          sp[wn * ROWS + rbase + mt * 16 + l4 * 4 + r] = p[mt][r];
    }
    __syncthreads();
#pragma unroll
    for (int mt = 0; mt < 4; ++mt)
#pragma unroll
      for (int r = 0; r < 4; ++r) {
        const int row = rbase + mt * 16 + l4 * 4 + r;
        const float sh = sp[row] + sp[ROWS + row] + sp[2 * ROWS + row] + sp[3 * ROWS + row];
        float w;
        if (h == 0) { s0[mt][r] = sh; lsum[mt][r] = 1.f; w = 1.f; }
        else {
          w = __expf(fminf(sh - s0[mt][r], 70.f));
          lsum[mt][r] += w;
        }
#pragma unroll
        for (int nt = 0; nt < 4; ++nt)
          ctx[mt][nt][r] = fmaf(w, acc[mt][nt][r], ctx[mt][nt][r]);
      }
    // next head's gemm barriers protect sp reuse
  }

  // normalize context, A := ctx
#pragma unroll
  for (int mt = 0; mt < 4; ++mt)
#pragma unroll
    for (int r = 0; r < 4; ++r) {
      const float inv = 1.f / lsum[mt][r];
#pragma unroll
      for (int nt = 0; nt < 4; ++nt) ctx[mt][nt][r] *= inv;
    }
  writeA(ctx, false);
  __syncthreads();

  // ---------------- fc3 + Wq epilogue ----------------
  gemm256(Wfc3, bfc3, acc);       // t1 pre-relu
  float wq[4];
#pragma unroll
  for (int nt = 0; nt < 4; ++nt) wq[nt] = Wq[cbase + nt * 16 + l15];
  float p[4][4];
#pragma unroll
  for (int mt = 0; mt < 4; ++mt)
#pragma unroll
    for (int r = 0; r < 4; ++r) {
      float v = 0.f;
#pragma unroll
      for (int nt = 0; nt < 4; ++nt)
        v = fmaf(fmaxf(acc[mt][nt][r], 0.f), wq[nt], v);
      p[mt][r] = v;
    }
#pragma unroll
  for (int off = 1; off < 16; off <<= 1)
#pragma unroll
    for (int mt = 0; mt < 4; ++mt)
#pragma unroll
      for (int r = 0; r < 4; ++r)
        p[mt][r] += __shfl_xor(p[mt][r], off, 64);
  if (l15 == 0) {
#pragma unroll
    for (int mt = 0; mt < 4; ++mt)
#pragma unroll
      for (int r = 0; r < 4; ++r)
        sp[wn * ROWS + rbase + mt * 16 + l4 * 4 + r] = p[mt][r];
  }
  __syncthreads();
  if (tid < ROWS) {
    out[row0 + tid] = sp[tid] + sp[ROWS + tid] + sp[2 * ROWS + tid]
                    + sp[3 * ROWS + tid] + bq[0];
  }
}

}  // namespace

extern "C" void kernel_launch(void* const* d_in, const int* in_sizes, int n_in,
                              void* d_out, int out_size, void* d_ws, size_t ws_size,
                              hipStream_t stream) {
  const float* x    = (const float*)d_in[0];
  const float* Wfc1 = (const float*)d_in[1];
  const float* bfc1 = (const float*)d_in[2];
  const float* Wfc2 = (const float*)d_in[3];
  const float* bfc2 = (const float*)d_in[4];
  const float* Wenc = (const float*)d_in[5];
  const float* benc = (const float*)d_in[6];
  const float* Whds = (const float*)d_in[7];
  const float* bhds = (const float*)d_in[8];
  const float* Wdec = (const float*)d_in[9];
  const float* bdec = (const float*)d_in[10];
  const float* Wfc3 = (const float*)d_in[11];
  const float* bfc3 = (const float*)d_in[12];
  const float* Wq   = (const float*)d_in[13];
  const float* bq   = (const float*)d_in[14];
  const int*  agent = (const int*)d_in[15];
  float* out = (float*)d_out;

  const int Bn = in_sizes[0] / INW;        // 32768
  const int grid = Bn / ROWS;              // 256 blocks

  fused_mfma<<<grid, NT, 0, stream>>>(x, Wfc1, bfc1, Wfc2, bfc2, Wenc, benc,
                                      Whds, bhds, Wdec, bdec, Wfc3, bfc3,
                                      Wq, bq, agent, out);
}

// Round 3
// 204.038 us; speedup vs baseline: 9.3893x; 1.5325x over previous
//
#include <hip/hip_runtime.h>
#include <hip/hip_bf16.h>

typedef _Float16 half8 __attribute__((ext_vector_type(8)));
typedef _Float16 half4 __attribute__((ext_vector_type(4)));
typedef _Float16 half2v __attribute__((ext_vector_type(2)));
typedef float f32x4 __attribute__((ext_vector_type(4)));

namespace {

constexpr int INW  = 87;
constexpr int ROWS = 64;    // rows per block
constexpr int NT   = 512;   // 8 waves

// ws layout (halves), all K padded to multiple of 32, n-major [256][K]
constexpr long O_FC1 = 0;        // [256][96], k<77 real
constexpr long O_FC2 = 24576;    // [256][32], k<10 real
constexpr long O_ENC = 32768;    // [256][256]
constexpr long O_HDS = 98304;    // 8 x [256][256]
constexpr long O_DEC = 622592;   // [256][256]
constexpr long O_FC3 = 688128;   // [256][256]
constexpr long W_TOTAL = 753664; // halves (1.44 MB)

__device__ __forceinline__ int aidx(int row, int col) {
  return row * 256 + ((((col >> 3) ^ (row & 7)) << 3) | (col & 7));
}

// -------- prep: transpose+convert f32 [K][256] -> fp16 [256][Kpad] --------
__global__ __launch_bounds__(256)
void prep_w(const float* __restrict__ Wfc1, const float* __restrict__ Wfc2,
            const float* __restrict__ Wenc, const float* __restrict__ Whds,
            const float* __restrict__ Wdec, const float* __restrict__ Wfc3,
            _Float16* __restrict__ ws)
{
  const long t = (long)blockIdx.x * 256 + threadIdx.x;
  const long e = t * 4;
  if (e >= W_TOTAL) return;
  const float* src; int K, Kreal; long base;
  if (e < O_FC2)      { src = Wfc1; K = 96;  Kreal = 77;  base = O_FC1; }
  else if (e < O_ENC) { src = Wfc2; K = 32;  Kreal = 10;  base = O_FC2; }
  else if (e < O_HDS) { src = Wenc; K = 256; Kreal = 256; base = O_ENC; }
  else if (e < O_DEC) { const long le = e - O_HDS; const int h = (int)(le >> 16);
                        src = Whds + ((long)h << 16); K = 256; Kreal = 256;
                        base = O_HDS + ((long)h << 16); }
  else if (e < O_FC3) { src = Wdec; K = 256; Kreal = 256; base = O_DEC; }
  else                { src = Wfc3; K = 256; Kreal = 256; base = O_FC3; }
  const long le = e - base;
  const int n = (int)(le / K), k0 = (int)(le % K);
  half4 v;
#pragma unroll
  for (int j = 0; j < 4; ++j) {
    const int k = k0 + j;
    v[j] = (_Float16)((k < Kreal) ? src[(size_t)k * 256 + n] : 0.f);
  }
  *(half4*)&ws[e] = v;
}

// -------- per-wave GEMM: C[64 x 32cols] += A[64 x K] * Wt[n][K]^T --------
template<int KS>
__device__ __forceinline__ void gemmT(const _Float16* __restrict__ A,
                                      const _Float16* __restrict__ Wt,
                                      const float* __restrict__ bias,
                                      int acol0, int l15, int l4, int cbase,
                                      f32x4 (&acc)[4][2])
{
#pragma unroll
  for (int nt = 0; nt < 2; ++nt) {
    const float bv = bias[cbase + nt * 16 + l15];
#pragma unroll
    for (int mt = 0; mt < 4; ++mt) acc[mt][nt] = { bv, bv, bv, bv };
  }
  constexpr int Klen = KS * 32;
#pragma unroll
  for (int ks = 0; ks < KS; ++ks) {
    const int k0 = ks * 32 + l4 * 8;
    half8 af[4], bf[2];
#pragma unroll
    for (int mt = 0; mt < 4; ++mt) {
      const int row = mt * 16 + l15;
      const int col = acol0 + k0;                       // 8-aligned
      af[mt] = *(const half8*)&A[row * 256 + (((col >> 3) ^ (row & 7)) << 3)];
    }
#pragma unroll
    for (int nt = 0; nt < 2; ++nt) {
      const int n = cbase + nt * 16 + l15;
      bf[nt] = *(const half8*)&Wt[(long)n * Klen + k0];
    }
#pragma unroll
    for (int mt = 0; mt < 4; ++mt)
#pragma unroll
      for (int nt = 0; nt < 2; ++nt)
        acc[mt][nt] = __builtin_amdgcn_mfma_f32_16x16x32_f16(
            af[mt], bf[nt], acc[mt][nt], 0, 0, 0);
  }
}

__device__ __forceinline__ void writeA(_Float16* __restrict__ A,
                                       const f32x4 (&acc)[4][2],
                                       int l15, int l4, int cbase, bool relu)
{
#pragma unroll
  for (int mt = 0; mt < 4; ++mt)
#pragma unroll
    for (int nt = 0; nt < 2; ++nt)
#pragma unroll
      for (int r = 0; r < 4; ++r) {
        float v = acc[mt][nt][r];
        if (relu) v = fmaxf(v, 0.f);
        const int row = mt * 16 + l4 * 4 + r;
        const int col = cbase + nt * 16 + l15;
        A[aidx(row, col)] = (_Float16)v;
      }
}

__global__ __launch_bounds__(NT, 4)
void fused_mfma(const float* __restrict__ x,
                const float* __restrict__ bfc1, const float* __restrict__ bfc2,
                const float* __restrict__ benc, const float* __restrict__ bhds,
                const float* __restrict__ bdec, const float* __restrict__ bfc3,
                const float* __restrict__ Wq,  const float* __restrict__ bq,
                const int* __restrict__ agent,
                const _Float16* __restrict__ ws,
                float* __restrict__ out)
{
  __shared__ _Float16 A[ROWS * 256];     // 32 KB
  __shared__ float sp[2][8][ROWS];       // 4 KB

  const int tid  = (int)threadIdx.x;
  const int lane = tid & 63;
  const int wn   = tid >> 6;        // 0..7 : 32-col stripe
  const int l15  = lane & 15;
  const int l4   = lane >> 4;
  const int cbase = wn * 32;
  const int row0 = (int)blockIdx.x * ROWS;
  const int a = agent[0];

  // ---- build A0 [64][128]: cols 0..76 enc-in, 96..105 dec-others, rest 0 ----
  for (int i = tid; i < ROWS * 128; i += NT) {
    const int r = i >> 7, c = i & 127;
    float v = 0.f;
    const size_t xb = (size_t)(row0 + r) * INW;
    if (c < 72)            v = x[xb + c];
    else if (c < 77)       v = x[xb + 72 + 5 * a + (c - 72)];
    else if (c >= 96 && c < 106) {
      const int o = c - 96;
      v = x[xb + 72 + (o < 5 * a ? o : o + 5)];
    }
    A[aidx(r, c)] = (_Float16)v;
  }
  __syncthreads();

  // ---- fc2 (K=32 @ col 96) and fc1 (K=96 @ col 0), both linear ----
  f32x4 accD[4][2], accE[4][2];
  gemmT<1>(A, ws + O_FC2, bfc2, 96, l15, l4, cbase, accD);
  gemmT<3>(A, ws + O_FC1, bfc1, 0,  l15, l4, cbase, accE);
  __syncthreads();

  writeA(A, accD, l15, l4, cbase, false);      // A := dec_in
  __syncthreads();

  f32x4 acc[4][2];
  gemmT<8>(A, ws + O_DEC, bdec, 0, l15, l4, cbase, acc);   // dec_H pre-relu
  half2v dpk[4][2][2];
#pragma unroll
  for (int mt = 0; mt < 4; ++mt)
#pragma unroll
    for (int nt = 0; nt < 2; ++nt)
#pragma unroll
      for (int rh = 0; rh < 2; ++rh)
        dpk[mt][nt][rh] = half2v{
            (_Float16)fmaxf(acc[mt][nt][2 * rh], 0.f),
            (_Float16)fmaxf(acc[mt][nt][2 * rh + 1], 0.f) };
  __syncthreads();

  writeA(A, accE, l15, l4, cbase, false);      // A := enc_in
  __syncthreads();
  gemmT<8>(A, ws + O_ENC, benc, 0, l15, l4, cbase, acc);   // enc_h
  __syncthreads();
  writeA(A, acc, l15, l4, cbase, true);        // A := relu(enc_h)
  __syncthreads();

  // ---- heads + online softmax (reference = head-0 score) ----
  f32x4 ctx[4][2];
#pragma unroll
  for (int mt = 0; mt < 4; ++mt)
#pragma unroll
    for (int nt = 0; nt < 2; ++nt) ctx[mt][nt] = { 0.f, 0.f, 0.f, 0.f };
  float s0[4][4], lsum[4][4];

  for (int h = 0; h < 8; ++h) {
    gemmT<8>(A, ws + O_HDS + (long)h * 65536, bhds + h * 256,
             0, l15, l4, cbase, acc);
#pragma unroll
    for (int mt = 0; mt < 4; ++mt)
#pragma unroll
      for (int nt = 0; nt < 2; ++nt)
#pragma unroll
        for (int r = 0; r < 4; ++r) acc[mt][nt][r] = fmaxf(acc[mt][nt][r], 0.f);

    float p[4][4];
#pragma unroll
    for (int mt = 0; mt < 4; ++mt)
#pragma unroll
      for (int r = 0; r < 4; ++r) {
        float v = 0.f;
#pragma unroll
        for (int nt = 0; nt < 2; ++nt)
          v = fmaf(acc[mt][nt][r], (float)dpk[mt][nt][r >> 1][r & 1], v);
        p[mt][r] = v;
      }
#pragma unroll
    for (int off = 1; off < 16; off <<= 1)
#pragma unroll
      for (int mt = 0; mt < 4; ++mt)
#pragma unroll
        for (int r = 0; r < 4; ++r)
          p[mt][r] += __shfl_xor(p[mt][r], off, 64);
    if (l15 == 0) {
#pragma unroll
      for (int mt = 0; mt < 4; ++mt)
#pragma unroll
        for (int r = 0; r < 4; ++r)
          sp[h & 1][wn][mt * 16 + l4 * 4 + r] = p[mt][r];
    }
    __syncthreads();
#pragma unroll
    for (int mt = 0; mt < 4; ++mt)
#pragma unroll
      for (int r = 0; r < 4; ++r) {
        const int row = mt * 16 + l4 * 4 + r;
        float sh = 0.f;
#pragma unroll
        for (int w = 0; w < 8; ++w) sh += sp[h & 1][w][row];
        float wgt;
        if (h == 0) { s0[mt][r] = sh; lsum[mt][r] = 1.f; wgt = 1.f; }
        else {
          wgt = __expf(fminf(sh - s0[mt][r], 70.f));
          lsum[mt][r] += wgt;
        }
#pragma unroll
        for (int nt = 0; nt < 2; ++nt)
          ctx[mt][nt][r] = fmaf(wgt, acc[mt][nt][r], ctx[mt][nt][r]);
      }
  }

#pragma unroll
  for (int mt = 0; mt < 4; ++mt)
#pragma unroll
    for (int r = 0; r < 4; ++r) {
      const float inv = 1.f / lsum[mt][r];
#pragma unroll
      for (int nt = 0; nt < 2; ++nt) ctx[mt][nt][r] *= inv;
    }
  __syncthreads();             // head-7 reads of A done
  writeA(A, ctx, l15, l4, cbase, false);       // A := context
  __syncthreads();

  // ---- fc3 (+relu) then @ Wq ----
  gemmT<8>(A, ws + O_FC3, bfc3, 0, l15, l4, cbase, acc);
  float wq[2];
#pragma unroll
  for (int nt = 0; nt < 2; ++nt) wq[nt] = Wq[cbase + nt * 16 + l15];
  float p[4][4];
#pragma unroll
  for (int mt = 0; mt < 4; ++mt)
#pragma unroll
    for (int r = 0; r < 4; ++r) {
      float v = 0.f;
#pragma unroll
      for (int nt = 0; nt < 2; ++nt)
        v = fmaf(fmaxf(acc[mt][nt][r], 0.f), wq[nt], v);
      p[mt][r] = v;
    }
#pragma unroll
  for (int off = 1; off < 16; off <<= 1)
#pragma unroll
    for (int mt = 0; mt < 4; ++mt)
#pragma unroll
      for (int r = 0; r < 4; ++r)
        p[mt][r] += __shfl_xor(p[mt][r], off, 64);
  if (l15 == 0) {
#pragma unroll
    for (int mt = 0; mt < 4; ++mt)
#pragma unroll
      for (int r = 0; r < 4; ++r)
        sp[0][wn][mt * 16 + l4 * 4 + r] = p[mt][r];
  }
  __syncthreads();
  if (tid < ROWS) {
    float v = bq[0];
#pragma unroll
    for (int w = 0; w < 8; ++w) v += sp[0][w][tid];
    out[row0 + tid] = v;
  }
}

}  // namespace

extern "C" void kernel_launch(void* const* d_in, const int* in_sizes, int n_in,
                              void* d_out, int out_size, void* d_ws, size_t ws_size,
                              hipStream_t stream) {
  const float* x    = (const float*)d_in[0];
  const float* Wfc1 = (const float*)d_in[1];
  const float* bfc1 = (const float*)d_in[2];
  const float* Wfc2 = (const float*)d_in[3];
  const float* bfc2 = (const float*)d_in[4];
  const float* Wenc = (const float*)d_in[5];
  const float* benc = (const float*)d_in[6];
  const float* Whds = (const float*)d_in[7];
  const float* bhds = (const float*)d_in[8];
  const float* Wdec = (const float*)d_in[9];
  const float* bdec = (const float*)d_in[10];
  const float* Wfc3 = (const float*)d_in[11];
  const float* bfc3 = (const float*)d_in[12];
  const float* Wq   = (const float*)d_in[13];
  const float* bq   = (const float*)d_in[14];
  const int*  agent = (const int*)d_in[15];
  float* out = (float*)d_out;
  _Float16* ws = (_Float16*)d_ws;

  const int Bn = in_sizes[0] / INW;         // 32768
  const int grid = Bn / ROWS;               // 512 blocks

  prep_w<<<(int)((W_TOTAL / 4 + 255) / 256), 256, 0, stream>>>(
      Wfc1, Wfc2, Wenc, Whds, Wdec, Wfc3, ws);
  fused_mfma<<<grid, NT, 0, stream>>>(x, bfc1, bfc2, benc, bhds, bdec, bfc3,
                                      Wq, bq, agent, ws, out);
}